// Round 14
// baseline (255.674 us; speedup 1.0000x reference)
//
#include <hip/hip_runtime.h>
#include <hip/hip_bf16.h>

typedef __attribute__((ext_vector_type(8))) short bf16x8;
typedef __attribute__((ext_vector_type(4))) float f32x4;

static constexpr int Tt = 2048;   // seq len
static constexpr int Cc = 1024;   // channels
static constexpr int Dd = 64;     // head dim
static constexpr int Mm = 8192;   // B*T

static constexpr size_t XN = (size_t)Mm * Cc;   // 8388608
static constexpr size_t WN = (size_t)Cc * Cc;   // 1048576

__device__ __forceinline__ void async_copy16(void* lds, const void* g) {
  __builtin_amdgcn_global_load_lds(
      (const __attribute__((address_space(1))) void*)g,
      (__attribute__((address_space(3))) void*)lds, 16, 0, 0);
}

__device__ __forceinline__ unsigned short f2bf(float f) {
  union { float f; unsigned int u; } v; v.f = f;
  unsigned int r = (v.u + 0x7fffu + ((v.u >> 16) & 1u)) >> 16;
  return (unsigned short)r;
}
__device__ __forceinline__ unsigned int pack2bf(float f0, float f1) {
  unsigned int b0 = __float_as_uint(f0) + 0x8000u;
  unsigned int b1 = __float_as_uint(f1) + 0x8000u;
  return (b1 & 0xffff0000u) | (b0 >> 16);
}
// single-instruction packed f32x2 -> bf16x2 (lo = f0, hi = f1); no builtin on
// gfx950 (m240) so inline asm. Pure VALU, no memory side effects.
__device__ __forceinline__ unsigned int cvtpk2bf(float f0, float f1) {
  unsigned int r;
  asm("v_cvt_pk_bf16_f32 %0, %1, %2" : "=v"(r) : "v"(f0), "v"(f1));
  return r;
}
__device__ __forceinline__ uint4 ldconv_f32(const float* p) {
  float4 lo = *(const float4*)p;
  float4 hi = *(const float4*)(p + 4);
  uint4 r;
  r.x = pack2bf(lo.x, lo.y);
  r.y = pack2bf(lo.z, lo.w);
  r.z = pack2bf(hi.x, hi.y);
  r.w = pack2bf(hi.z, hi.w);
  return r;
}

// f32 -> bf16 pre-convert of X, Wq, Wk, Wv into d_out scratch (23.1MB) and
// Wp into workspace — merged to save one kernel launch. Blocks >=5632
// handle Wp (only launched when the workspace fits Wpb).
__global__ __launch_bounds__(256) void convert_all(
    const float* __restrict__ x, const float* __restrict__ wq,
    const float* __restrict__ wk, const float* __restrict__ wv,
    unsigned short* __restrict__ dst,
    const float* __restrict__ wp, unsigned short* __restrict__ wpb)
{
  if (blockIdx.x >= 5632) {
    const size_t i = ((size_t)(blockIdx.x - 5632) * 256 + threadIdx.x) * 8;
    *(uint4*)(wpb + i) = ldconv_f32(wp + i);
    return;
  }
  const size_t i = ((size_t)blockIdx.x * 256 + threadIdx.x) * 8;
  const float* s; size_t off;
  if (i < XN)                { s = x;  off = 0; }
  else if (i < XN + WN)      { s = wq; off = XN; }
  else if (i < XN + 2 * WN)  { s = wk; off = XN + WN; }
  else                       { s = wv; off = XN + 2 * WN; }
  *(uint4*)(dst + i) = ldconv_f32(s + (i - off));
}

// NT GEMM, all-bf16 inputs. BK=64 (R9-verified). 2-barrier single-buffer
// (best for global_load_lds staging, R6/R7 A/B). Swizzle for 128-B rows:
//   source pre-swizzle g = ch ^ (row&7); read chan chp = (kk*4+quad)^(m16&7)
// -> exactly 2 lanes/bank (free, m136); bank-conflict = 0 (R9-verified).
// MODE 0: bf16 out[m*Cc+n]*mult+bias. MODE 1 (V): bf16 out[(b*Cc+n)*Tt+t].
// MODE 2: f32 out[m*Cc+n] = acc + bias (proj).
template <int MODE>
__device__ __forceinline__ void gemm_async_body(
    unsigned short* As, unsigned short* Bs,   // each [8192] shorts (16KB)
    const unsigned short* __restrict__ A,
    const unsigned short* __restrict__ Bt,
    const float* __restrict__ bias,
    unsigned short* __restrict__ out, float mult)
{
  const int tid  = threadIdx.x;
  const int wave = tid >> 6;
  const int lane = tid & 63;
  const int m16  = lane & 15;
  const int quad = lane >> 4;
  const int row0 = blockIdx.x * 128;
  const int col0 = blockIdx.y * 128;
  const int wm = (wave >> 1) * 64;
  const int wn = (wave & 1) * 64;

  f32x4 acc[4][4] = {};

  // staging slots: c = j*256 + tid, j=0..3; row = c>>3, lds chan = c&7,
  // global chan = (c&7)^((c>>3)&7). LDS dest is linear: byte = c*16.
  const unsigned short* Ag[4];
  const unsigned short* Bg[4];
#pragma unroll
  for (int j = 0; j < 4; ++j) {
    const int c  = j * 256 + tid;
    const int rw = c >> 3;
    const int sw = (c & 7) ^ (rw & 7);
    Ag[j] = A  + (size_t)(row0 + rw) * Cc + sw * 8;
    Bg[j] = Bt + (size_t)(col0 + rw) * Cc + sw * 8;
  }

  for (int k0 = 0; k0 < Cc; k0 += 64) {
    __syncthreads();
#pragma unroll
    for (int j = 0; j < 4; ++j)
      async_copy16((char*)As + j * 4096 + wave * 1024, Ag[j] + k0);
#pragma unroll
    for (int j = 0; j < 4; ++j)
      async_copy16((char*)Bs + j * 4096 + wave * 1024, Bg[j] + k0);
    __syncthreads();
#pragma unroll
    for (int kk = 0; kk < 2; ++kk) {
      const int chp = (kk * 4 + quad) ^ (m16 & 7);
      bf16x8 af[4], bfr[4];
#pragma unroll
      for (int i = 0; i < 4; ++i)
        af[i] = *(const bf16x8*)(As + (wm + i * 16 + m16) * 64 + chp * 8);
#pragma unroll
      for (int j = 0; j < 4; ++j)
        bfr[j] = *(const bf16x8*)(Bs + (wn + j * 16 + m16) * 64 + chp * 8);
#pragma unroll
      for (int i = 0; i < 4; ++i)
#pragma unroll
        for (int j = 0; j < 4; ++j)
          acc[i][j] = __builtin_amdgcn_mfma_f32_16x16x32_bf16(af[i], bfr[j], acc[i][j], 0, 0, 0);
    }
  }

  // epilogue; bias has only 4 distinct values per thread (col indep of i)
  float bvj[4];
#pragma unroll
  for (int j = 0; j < 4; ++j)
    bvj[j] = bias[col0 + wn + j * 16 + m16];
#pragma unroll
  for (int i = 0; i < 4; ++i) {
    const int rbase = row0 + wm + i * 16 + quad * 4;
#pragma unroll
    for (int j = 0; j < 4; ++j) {
      const int col = col0 + wn + j * 16 + m16;
      const float bv = bvj[j];
      if (MODE == 0) {
#pragma unroll
        for (int r = 0; r < 4; ++r)
          out[(size_t)(rbase + r) * Cc + col] = f2bf((acc[i][j][r] + bv) * mult);
      } else if (MODE == 1) {
        const int t0 = rbase & (Tt - 1);
        const int b  = rbase >> 11;
        ushort4 pk;
        pk.x = f2bf(acc[i][j][0] + bv);
        pk.y = f2bf(acc[i][j][1] + bv);
        pk.z = f2bf(acc[i][j][2] + bv);
        pk.w = f2bf(acc[i][j][3] + bv);
        *(ushort4*)(out + (size_t)(b * Cc + col) * Tt + t0) = pk;
      } else {
        float* outf = (float*)out;
#pragma unroll
        for (int r = 0; r < 4; ++r)
          outf[(size_t)(rbase + r) * Cc + col] = acc[i][j][r] + bv;
      }
    }
  }
}

__global__ __launch_bounds__(256) void qkv_gemm(
    const unsigned short* __restrict__ Xb,
    const unsigned short* __restrict__ Wqb, const float* __restrict__ bq,
    const unsigned short* __restrict__ Wkb, const float* __restrict__ bk,
    const unsigned short* __restrict__ Wvb, const float* __restrict__ bv,
    unsigned short* Qw, unsigned short* Kw, unsigned short* Vtw)
{
  __shared__ __align__(16) unsigned short smem[16384];  // 32KB: A[8192] B[8192]
  const int z = blockIdx.z;
  // Q scale folds 1/sqrt(d) AND log2(e) so attention uses exp2 directly.
  if (z == 0)      gemm_async_body<0>(smem, smem + 8192, Xb, Wqb, bq, Qw, 0.125f * 1.44269504f);
  else if (z == 1) gemm_async_body<0>(smem, smem + 8192, Xb, Wkb, bk, Kw, 1.0f);
  else             gemm_async_body<1>(smem, smem + 8192, Xb, Wvb, bv, Vtw, 1.0f);
}

// proj with pre-converted bf16 Wp — identical structure to a qkv slice.
__global__ __launch_bounds__(256) void proj_gemm_pre(
    const unsigned short* __restrict__ Yb,
    const unsigned short* __restrict__ Wpb, const float* __restrict__ bp,
    float* __restrict__ out)
{
  __shared__ __align__(16) unsigned short smem[16384];
  gemm_async_body<2>(smem, smem + 8192, Yb, Wpb, bp, (unsigned short*)out, 1.0f);
}

// Wave-per-strip-pair flash attention.
// R14: 2-WAVE BLOCKS, grid (bh=64, p=16). Pairing j = 2p+wave gives heavy
// strip 63-2p-w, light 2p+w; BOTH waves in a block get IDENTICAL tile
// counts (heavy nk = 32-p, light nk = p+1 for w=0 and w=1) — zero
// intra-block idle (the 4-wave version had up to 2-tile wave spread at
// every barrier), TOT drops 34 -> 33, barriers couple only 2 waves, and
// 1024 blocks -> 4 blocks/CU of independent staging streams (same
// 8 waves/CU). Staging: 8 copies/thread, cc = ii*128+tid, dest base
// ii*2048 + wave*1024 (wave-uniform; HW adds lane*16).
// XCD-aware grid (R10-verified: FETCH 147.5 -> 34MB): bh fastest, XCD=bh%8.
// TRANSPOSED algebra:
//   S^T = K.Q^T (C-layout: col=q on m16, row=key=quad*4+r per 16-block jn)
//   O^T = V^T.P^T; P^T B-frag built ENTIRELY in-register via
//   permlane32_swap + permlane16_swap pairs (verified: 0 bank conflicts).
// VALU diet (R5, verified): cvt_pk pack; lsum via ones-row MFMA (lane's
// lz[s][0] = full denominator, no shuffles in writeout).
// s_setprio(1) wrapped around MFMA clusters (T5, attn-positive per m191).
__global__ __launch_bounds__(128) void attn_pair(
    const unsigned short* __restrict__ Q,
    const unsigned short* __restrict__ Kg,
    const unsigned short* __restrict__ Vt,
    unsigned short* __restrict__ Y)
{
  __shared__ __align__(16) unsigned short KV[2 * 8192];  // [buf][K 4096h | V 4096h]

  const int tid  = threadIdx.x;               // 0..127
  const int wave = tid >> 6;                  // 0..1
  const int lane = tid & 63;
  const int m16  = lane & 15;
  const int quad = lane >> 4;

  const int bh = blockIdx.x;                  // bh fastest -> XCD = bh%8
  const int p  = blockIdx.y;                  // 0..15
  const int b = bh >> 4, h = bh & 15;

  const unsigned short* Kb = Kg + (size_t)(b * Tt) * Cc + h * Dd;
  const unsigned short* Vb = Vt + (size_t)(b * Cc + h * Dd) * Tt;

  const int maxH = 32 - p;                    // heavy tiles (= heavy nk, both waves)
  const int TOT  = 33;                        // maxH + (p+1), constant
  const int chp  = quad ^ ((m16 >> 1) & 3);   // swizzled read channel

  bf16x8 onesA;
#pragma unroll
  for (int i = 0; i < 8; ++i) onesA[i] = (short)0x3F80;  // bf16 1.0

  // staging: 8 copies/thread (cc = ii*128 + tid covers 512 slots/tile);
  // pointers advance by fixed strides, wrap-reset by uniform subtraction.
  const unsigned short* pK[4];
  const unsigned short* pV[4];
#pragma unroll
  for (int ii = 0; ii < 4; ++ii) {
    const int cc  = ii * 128 + tid;
    const int kkS = cc >> 8;
    const int rrS = (cc >> 2) & 63;
    const int chd = (cc & 3) ^ ((rrS >> 1) & 3);
    pK[ii] = Kb + (size_t)rrS * Cc + kkS * 32 + chd * 8;
    pV[ii] = Vb + (size_t)rrS * Tt + kkS * 32 + chd * 8;
  }

  // phase-0 (heavy) strip state
  int sidx = 63 - 2 * p - wave;
  int qw = sidx * 32;
  int nk = (sidx >> 1) + 1;                   // = maxH for both waves
  bf16x8 qf[2][2];
  {
    const unsigned short* Qb = Q + (size_t)(b * Tt + qw) * Cc + h * Dd;
#pragma unroll
    for (int s = 0; s < 2; ++s)
#pragma unroll
      for (int kk = 0; kk < 2; ++kk)
        qf[s][kk] = *(const bf16x8*)(Qb + (size_t)(s * 16 + m16) * Cc + kk * 32 + quad * 8);
  }
  f32x4 o[2][4] = {};
  f32x4 lz[2] = {};                           // ones-MFMA denominator accumulator

  auto writeout = [&](int qw_) {
#pragma unroll
    for (int s = 0; s < 2; ++s) {
      const float l = lz[s][0];               // full sum for q=m16, no shuffle
      const float inv = (l > 0.f) ? (1.0f / l) : 0.f;
      const int t = qw_ + s * 16 + m16;
      unsigned short* yp = Y + (size_t)(b * Tt + t) * Cc + h * Dd + quad * 4;
#pragma unroll
      for (int jn = 0; jn < 4; ++jn) {
        uint2 pk;
        pk.x = cvtpk2bf(o[s][jn][0] * inv, o[s][jn][1] * inv);
        pk.y = cvtpk2bf(o[s][jn][2] * inv, o[s][jn][3] * inv);
        *(uint2*)(yp + jn * 16) = pk;
      }
    }
  };

  // prologue: stage tile 0 into buf 0, advance pointers to tile 1
  {
    char* KbufB = (char*)KV;
    char* VbufB = KbufB + 8192;
#pragma unroll
    for (int ii = 0; ii < 4; ++ii) {
      async_copy16(KbufB + ii * 2048 + wave * 1024, pK[ii]);
      async_copy16(VbufB + ii * 2048 + wave * 1024, pV[ii]);
    }
#pragma unroll
    for (int ii = 0; ii < 4; ++ii) { pK[ii] += 64 * Cc; pV[ii] += 64; }
  }

  for (int g = 0; g < TOT; ++g) {
    if (g == maxH) {                          // heavy strip done -> switch to light
      writeout(qw);
      sidx = 2 * p + wave;
      qw = sidx * 32;
      nk = (sidx >> 1) + 1;                   // = p+1 for both waves
      const unsigned short* Qb = Q + (size_t)(b * Tt + qw) * Cc + h * Dd;
#pragma unroll
      for (int s = 0; s < 2; ++s) {
#pragma unroll
        for (int kk = 0; kk < 2; ++kk)
          qf[s][kk] = *(const bf16x8*)(Qb + (size_t)(s * 16 + m16) * Cc + kk * 32 + quad * 8);
#pragma unroll
        for (int jn = 0; jn < 4; ++jn)
          o[s][jn] = f32x4{0.f, 0.f, 0.f, 0.f};
        lz[s] = f32x4{0.f, 0.f, 0.f, 0.f};
      }
    }
    const int kt  = (g < maxH) ? g : g - maxH;
    const int k0  = kt * 64;
    const int buf = g & 1;

    __syncthreads();                          // copies for g drained; prior LDS reads done
    if (g + 1 < TOT) {                        // prefetch tile g+1 into other buffer
      if (g + 1 == maxH) {                    // wrap: light phase restarts at tile 0
#pragma unroll
        for (int ii = 0; ii < 4; ++ii) {
          pK[ii] -= (size_t)maxH * 64 * Cc;
          pV[ii] -= (size_t)maxH * 64;
        }
      }
      char* KbufB = (char*)KV + (buf ^ 1) * 16384;
      char* VbufB = KbufB + 8192;
#pragma unroll
      for (int ii = 0; ii < 4; ++ii) {
        async_copy16(KbufB + ii * 2048 + wave * 1024, pK[ii]);
        async_copy16(VbufB + ii * 2048 + wave * 1024, pV[ii]);
      }
#pragma unroll
      for (int ii = 0; ii < 4; ++ii) { pK[ii] += 64 * Cc; pV[ii] += 64; }
    }

    if (kt < nk) {                            // wave-uniform (always true; kept for safety)
      const unsigned short* Kbuf = KV + buf * 8192;
      const unsigned short* Vbuf = Kbuf + 4096;
      bf16x8 kf[2][4], vf[2][4];
#pragma unroll
      for (int kk = 0; kk < 2; ++kk)
#pragma unroll
        for (int jn = 0; jn < 4; ++jn) {
          kf[kk][jn] = *(const bf16x8*)(Kbuf + kk * 2048 + (jn * 16 + m16) * 32 + chp * 8);
          vf[kk][jn] = *(const bf16x8*)(Vbuf + kk * 2048 + (jn * 16 + m16) * 32 + chp * 8);
        }

#pragma unroll
      for (int s = 0; s < 2; ++s) {
        const int smin = qw + s * 16;
        if (k0 > smin + 15) continue;         // sub-strip fully masked
        // S^T = K.Q^T : C-layout lane m16 = q, reg (jn,r) = key jn*16+quad*4+r
        f32x4 sv[4] = {};
        __builtin_amdgcn_s_setprio(1);
#pragma unroll
        for (int kk = 0; kk < 2; ++kk)
#pragma unroll
          for (int jn = 0; jn < 4; ++jn)
            sv[jn] = __builtin_amdgcn_mfma_f32_16x16x32_bf16(kf[kk][jn], qf[s][kk], sv[jn], 0, 0, 0);
        __builtin_amdgcn_s_setprio(0);

        if (k0 + 63 <= smin) {                // fully unmasked: bare exp2
#pragma unroll
          for (int jn = 0; jn < 4; ++jn)
#pragma unroll
            for (int r = 0; r < 4; ++r)
              sv[jn][r] = __builtin_exp2f(sv[jn][r]);
        } else {                               // diagonal: causal mask
          const int qcol = smin + m16;
#pragma unroll
          for (int jn = 0; jn < 4; ++jn)
#pragma unroll
            for (int r = 0; r < 4; ++r)
              sv[jn][r] = (k0 + jn * 16 + quad * 4 + r > qcol)
                              ? 0.f : __builtin_exp2f(sv[jn][r]);
        }

        // pack key-pairs into bf16x2 words (1 cvt_pk each)
        unsigned int P2[4][2];
#pragma unroll
        for (int jn = 0; jn < 4; ++jn) {
          P2[jn][0] = cvtpk2bf(sv[jn][0], sv[jn][1]);
          P2[jn][1] = cvtpk2bf(sv[jn][2], sv[jn][3]);
        }
        // in-register P^T B-frag build: 2 permlane ops per word-pair
#pragma unroll
        for (int kk = 0; kk < 2; ++kk) {
          auto r0 = __builtin_amdgcn_permlane32_swap(P2[2 * kk][0], P2[2 * kk + 1][0], false, false);
          auto t0 = __builtin_amdgcn_permlane16_swap(r0[0], r0[1], false, false);
          auto r1 = __builtin_amdgcn_permlane32_swap(P2[2 * kk][1], P2[2 * kk + 1][1], false, false);
          auto t1 = __builtin_amdgcn_permlane16_swap(r1[0], r1[1], false, false);
          uint4 u;
          u.x = t0[0];                        // sigma=0, w=0
          u.y = t1[0];                        // sigma=0, w=1
          u.z = t0[1];                        // sigma=1, w=0
          u.w = t1[1];                        // sigma=1, w=1
          union { uint4 u4; bf16x8 bf; } cv; cv.u4 = u;
          // O^T += V^T . P^T ; lz += ones . P^T (denominator on matrix pipe)
          __builtin_amdgcn_s_setprio(1);
          lz[s] = __builtin_amdgcn_mfma_f32_16x16x32_bf16(onesA, cv.bf, lz[s], 0, 0, 0);
#pragma unroll
          for (int jn = 0; jn < 4; ++jn)
            o[s][jn] = __builtin_amdgcn_mfma_f32_16x16x32_bf16(vf[kk][jn], cv.bf, o[s][jn], 0, 0, 0);
          __builtin_amdgcn_s_setprio(0);
        }
      }
    }
  }

  writeout(qw);                               // light strip
}

// proj fallback (ws too small for Wpb): A = Yw bf16 (async staging),
// B = Wp f32 (register-convert, dbuf: T14 issue-early/write-late), f32 out.
__global__ __launch_bounds__(256) void proj_gemm(
    const unsigned short* __restrict__ Y,
    const float* __restrict__ Wp, const float* __restrict__ bp,
    float* __restrict__ out)
{
  __shared__ __align__(16) unsigned short As[8192];   // [2][4096]
  __shared__ __align__(16) unsigned short Bs[8192];   // [2][4096]
  const int tid  = threadIdx.x;
  const int wave = tid >> 6;
  const int lane = tid & 63;
  const int m16  = lane & 15;
  const int quad = lane >> 4;
  const int row0 = blockIdx.x * 128;
  const int col0 = blockIdx.y * 128;
  const int wm = (wave >> 1) * 64;
  const int wn = (wave & 1) * 64;
  const int chp = quad ^ ((m16 >> 1) & 3);    // swizzled read channel

  f32x4 acc[4][4] = {};

  const int c0 = tid, c1 = 256 + tid;
  const int sw0 = (c0 & 3) ^ ((c0 >> 3) & 3);
  const int sw1 = (c1 & 3) ^ ((c1 >> 3) & 3);
  const unsigned short* Ag0 = Y + (size_t)(row0 + (c0 >> 2)) * Cc + sw0 * 8;
  const unsigned short* Ag1 = Y + (size_t)(row0 + (c1 >> 2)) * Cc + sw1 * 8;
  const float* Bg0 = Wp + (size_t)(col0 + (c0 >> 2)) * Cc + (c0 & 3) * 8;
  const float* Bg1 = Wp + (size_t)(col0 + (c1 >> 2)) * Cc + (c1 & 3) * 8;
  // swizzled LDS write offsets for the B panel (shorts)
  const int bd0 = ((c0 >> 2) * 4 + sw0) * 8;
  const int bd1 = ((c1 >> 2) * 4 + sw1) * 8;

  uint4 b0 = ldconv_f32(Bg0);
  uint4 b1 = ldconv_f32(Bg1);

  // prologue: stage A k=0 into buf0; write B k=0 into buf0; preload B k=32
  async_copy16((char*)As + wave * 1024,        Ag0);
  async_copy16((char*)As + 4096 + wave * 1024, Ag1);
  *(uint4*)(Bs + bd0) = b0;
  *(uint4*)(Bs + bd1) = b1;
  b0 = ldconv_f32(Bg0 + 32);
  b1 = ldconv_f32(Bg1 + 32);

  int buf = 0;
  for (int k0 = 0; k0 < Cc; k0 += 32) {
    __syncthreads();                          // buf A-copies drained; buf B-writes visible
    if (k0 + 32 < Cc) {
      char* Ab = (char*)As + (buf ^ 1) * 8192;
      async_copy16(Ab + wave * 1024,        Ag0 + k0 + 32);
      async_copy16(Ab + 4096 + wave * 1024, Ag1 + k0 + 32);
      *(uint4*)(Bs + (buf ^ 1) * 4096 + bd0) = b0;
      *(uint4*)(Bs + (buf ^ 1) * 4096 + bd1) = b1;
      if (k0 + 64 < Cc) {
        b0 = ldconv_f32(Bg0 + k0 + 64);
        b1 = ldconv_f32(Bg1 + k0 + 64);
      }
    }
    const unsigned short* Asb = As + buf * 4096;
    const unsigned short* Bsb = Bs + buf * 4096;
    bf16x8 af[4], bfr[4];
#pragma unroll
    for (int i = 0; i < 4; ++i)
      af[i] = *(const bf16x8*)(Asb + (wm + i * 16 + m16) * 32 + chp * 8);
#pragma unroll
    for (int j = 0; j < 4; ++j)
      bfr[j] = *(const bf16x8*)(Bsb + (wn + j * 16 + m16) * 32 + chp * 8);
#pragma unroll
    for (int i = 0; i < 4; ++i)
#pragma unroll
      for (int j = 0; j < 4; ++j)
        acc[i][j] = __builtin_amdgcn_mfma_f32_16x16x32_bf16(af[i], bfr[j], acc[i][j], 0, 0, 0);
    buf ^= 1;
  }

#pragma unroll
  for (int i = 0; i < 4; ++i) {
    const int rbase = row0 + wm + i * 16 + quad * 4;
#pragma unroll
    for (int j = 0; j < 4; ++j) {
      const int col = col0 + wn + j * 16 + m16;
      const float bv = bp[col];
#pragma unroll
      for (int r = 0; r < 4; ++r)
        out[(size_t)(rbase + r) * Cc + col] = acc[i][j][r] + bv;
    }
  }
}

extern "C" void kernel_launch(void* const* d_in, const int* in_sizes, int n_in,
                              void* d_out, int out_size, void* d_ws, size_t ws_size,
                              hipStream_t stream)
{
  const float* x  = (const float*)d_in[0];
  const float* Wq = (const float*)d_in[1];
  const float* bq = (const float*)d_in[2];
  const float* Wk = (const float*)d_in[3];
  const float* bk = (const float*)d_in[4];
  const float* Wv = (const float*)d_in[5];
  const float* bv = (const float*)d_in[6];
  const float* Wp = (const float*)d_in[7];
  const float* bp = (const float*)d_in[8];

  unsigned short* ws  = (unsigned short*)d_ws;
  unsigned short* Qw  = ws;                          // bf16 [8192][1024] (scale folded)
  unsigned short* Kw  = ws + (size_t)1 * XN;         // bf16 [8192][1024]
  unsigned short* Vtw = ws + (size_t)2 * XN;         // bf16 [b*1024 + n][2048]
  unsigned short* Yw  = ws + (size_t)3 * XN;         // bf16 [8192][1024]
  unsigned short* Wpb = ws + (size_t)4 * XN;         // bf16 [1024][1024] (if ws fits)
  const bool pre = ws_size >= ((size_t)4 * XN + WN) * sizeof(unsigned short);

  // d_out doubles as bf16 scratch for converted X/Wq/Wk/Wv; proj overwrites last.
  unsigned short* cvt = (unsigned short*)d_out;
  unsigned short* Xb  = cvt;
  unsigned short* Wqb = cvt + XN;
  unsigned short* Wkb = cvt + XN + WN;
  unsigned short* Wvb = cvt + XN + 2 * WN;
  float* out = (float*)d_out;

  convert_all<<<pre ? 6144 : 5632, 256, 0, stream>>>(x, Wq, Wk, Wv, cvt, Wp, Wpb);
  qkv_gemm<<<dim3(64, 8, 3), 256, 0, stream>>>(Xb, Wqb, bq, Wkb, bk, Wvb, bv, Qw, Kw, Vtw);
  attn_pair<<<dim3(64, 16), 128, 0, stream>>>(Qw, Kw, Vtw, Yw);  // bh fastest -> XCD=bh%8
  if (pre) proj_gemm_pre<<<dim3(64, 8), 256, 0, stream>>>(Yw, Wpb, bp, out);
  else     proj_gemm<<<dim3(64, 8), 256, 0, stream>>>(Yw, Wp, bp, out);
}

// Round 15
// 251.605 us; speedup vs baseline: 1.0162x; 1.0162x over previous
//
#include <hip/hip_runtime.h>
#include <hip/hip_bf16.h>

typedef __attribute__((ext_vector_type(8))) short bf16x8;
typedef __attribute__((ext_vector_type(4))) float f32x4;

static constexpr int Tt = 2048;   // seq len
static constexpr int Cc = 1024;   // channels
static constexpr int Dd = 64;     // head dim
static constexpr int Mm = 8192;   // B*T

static constexpr size_t XN = (size_t)Mm * Cc;   // 8388608
static constexpr size_t WN = (size_t)Cc * Cc;   // 1048576

__device__ __forceinline__ void async_copy16(void* lds, const void* g) {
  __builtin_amdgcn_global_load_lds(
      (const __attribute__((address_space(1))) void*)g,
      (__attribute__((address_space(3))) void*)lds, 16, 0, 0);
}

__device__ __forceinline__ unsigned short f2bf(float f) {
  union { float f; unsigned int u; } v; v.f = f;
  unsigned int r = (v.u + 0x7fffu + ((v.u >> 16) & 1u)) >> 16;
  return (unsigned short)r;
}
__device__ __forceinline__ unsigned int pack2bf(float f0, float f1) {
  unsigned int b0 = __float_as_uint(f0) + 0x8000u;
  unsigned int b1 = __float_as_uint(f1) + 0x8000u;
  return (b1 & 0xffff0000u) | (b0 >> 16);
}
// single-instruction packed f32x2 -> bf16x2 (lo = f0, hi = f1); no builtin on
// gfx950 (m240) so inline asm. Pure VALU, no memory side effects.
__device__ __forceinline__ unsigned int cvtpk2bf(float f0, float f1) {
  unsigned int r;
  asm("v_cvt_pk_bf16_f32 %0, %1, %2" : "=v"(r) : "v"(f0), "v"(f1));
  return r;
}
__device__ __forceinline__ uint4 ldconv_f32(const float* p) {
  float4 lo = *(const float4*)p;
  float4 hi = *(const float4*)(p + 4);
  uint4 r;
  r.x = pack2bf(lo.x, lo.y);
  r.y = pack2bf(lo.z, lo.w);
  r.z = pack2bf(hi.x, hi.y);
  r.w = pack2bf(hi.z, hi.w);
  return r;
}

// f32 -> bf16 pre-convert of X, Wq, Wk, Wv into d_out scratch (23.1MB) and
// Wp into workspace — merged to save one kernel launch. Blocks >=5632
// handle Wp (only launched when the workspace fits Wpb).
__global__ __launch_bounds__(256) void convert_all(
    const float* __restrict__ x, const float* __restrict__ wq,
    const float* __restrict__ wk, const float* __restrict__ wv,
    unsigned short* __restrict__ dst,
    const float* __restrict__ wp, unsigned short* __restrict__ wpb)
{
  if (blockIdx.x >= 5632) {
    const size_t i = ((size_t)(blockIdx.x - 5632) * 256 + threadIdx.x) * 8;
    *(uint4*)(wpb + i) = ldconv_f32(wp + i);
    return;
  }
  const size_t i = ((size_t)blockIdx.x * 256 + threadIdx.x) * 8;
  const float* s; size_t off;
  if (i < XN)                { s = x;  off = 0; }
  else if (i < XN + WN)      { s = wq; off = XN; }
  else if (i < XN + 2 * WN)  { s = wk; off = XN + WN; }
  else                       { s = wv; off = XN + 2 * WN; }
  *(uint4*)(dst + i) = ldconv_f32(s + (i - off));
}

// NT GEMM, all-bf16 inputs. BK=64 (R9-verified). 2-barrier single-buffer
// (best for global_load_lds staging, R6/R7 A/B). Swizzle for 128-B rows:
//   source pre-swizzle g = ch ^ (row&7); read chan chp = (kk*4+quad)^(m16&7)
// -> exactly 2 lanes/bank (free, m136); bank-conflict = 0 (R9-verified).
// MODE 0: bf16 out[m*Cc+n]*mult+bias. MODE 1 (V): bf16 out[(b*Cc+n)*Tt+t].
// MODE 2: f32 out[m*Cc+n] = acc + bias (proj).
template <int MODE>
__device__ __forceinline__ void gemm_async_body(
    unsigned short* As, unsigned short* Bs,   // each [8192] shorts (16KB)
    const unsigned short* __restrict__ A,
    const unsigned short* __restrict__ Bt,
    const float* __restrict__ bias,
    unsigned short* __restrict__ out, float mult)
{
  const int tid  = threadIdx.x;
  const int wave = tid >> 6;
  const int lane = tid & 63;
  const int m16  = lane & 15;
  const int quad = lane >> 4;
  const int row0 = blockIdx.x * 128;
  const int col0 = blockIdx.y * 128;
  const int wm = (wave >> 1) * 64;
  const int wn = (wave & 1) * 64;

  f32x4 acc[4][4] = {};

  // staging slots: c = j*256 + tid, j=0..3; row = c>>3, lds chan = c&7,
  // global chan = (c&7)^((c>>3)&7). LDS dest is linear: byte = c*16.
  const unsigned short* Ag[4];
  const unsigned short* Bg[4];
#pragma unroll
  for (int j = 0; j < 4; ++j) {
    const int c  = j * 256 + tid;
    const int rw = c >> 3;
    const int sw = (c & 7) ^ (rw & 7);
    Ag[j] = A  + (size_t)(row0 + rw) * Cc + sw * 8;
    Bg[j] = Bt + (size_t)(col0 + rw) * Cc + sw * 8;
  }

  for (int k0 = 0; k0 < Cc; k0 += 64) {
    __syncthreads();
#pragma unroll
    for (int j = 0; j < 4; ++j)
      async_copy16((char*)As + j * 4096 + wave * 1024, Ag[j] + k0);
#pragma unroll
    for (int j = 0; j < 4; ++j)
      async_copy16((char*)Bs + j * 4096 + wave * 1024, Bg[j] + k0);
    __syncthreads();
#pragma unroll
    for (int kk = 0; kk < 2; ++kk) {
      const int chp = (kk * 4 + quad) ^ (m16 & 7);
      bf16x8 af[4], bfr[4];
#pragma unroll
      for (int i = 0; i < 4; ++i)
        af[i] = *(const bf16x8*)(As + (wm + i * 16 + m16) * 64 + chp * 8);
#pragma unroll
      for (int j = 0; j < 4; ++j)
        bfr[j] = *(const bf16x8*)(Bs + (wn + j * 16 + m16) * 64 + chp * 8);
#pragma unroll
      for (int i = 0; i < 4; ++i)
#pragma unroll
        for (int j = 0; j < 4; ++j)
          acc[i][j] = __builtin_amdgcn_mfma_f32_16x16x32_bf16(af[i], bfr[j], acc[i][j], 0, 0, 0);
    }
  }

  // epilogue; bias has only 4 distinct values per thread (col indep of i)
  float bvj[4];
#pragma unroll
  for (int j = 0; j < 4; ++j)
    bvj[j] = bias[col0 + wn + j * 16 + m16];
#pragma unroll
  for (int i = 0; i < 4; ++i) {
    const int rbase = row0 + wm + i * 16 + quad * 4;
#pragma unroll
    for (int j = 0; j < 4; ++j) {
      const int col = col0 + wn + j * 16 + m16;
      const float bv = bvj[j];
      if (MODE == 0) {
#pragma unroll
        for (int r = 0; r < 4; ++r)
          out[(size_t)(rbase + r) * Cc + col] = f2bf((acc[i][j][r] + bv) * mult);
      } else if (MODE == 1) {
        const int t0 = rbase & (Tt - 1);
        const int b  = rbase >> 11;
        ushort4 pk;
        pk.x = f2bf(acc[i][j][0] + bv);
        pk.y = f2bf(acc[i][j][1] + bv);
        pk.z = f2bf(acc[i][j][2] + bv);
        pk.w = f2bf(acc[i][j][3] + bv);
        *(ushort4*)(out + (size_t)(b * Cc + col) * Tt + t0) = pk;
      } else {
        float* outf = (float*)out;
#pragma unroll
        for (int r = 0; r < 4; ++r)
          outf[(size_t)(rbase + r) * Cc + col] = acc[i][j][r] + bv;
      }
    }
  }
}

__global__ __launch_bounds__(256) void qkv_gemm(
    const unsigned short* __restrict__ Xb,
    const unsigned short* __restrict__ Wqb, const float* __restrict__ bq,
    const unsigned short* __restrict__ Wkb, const float* __restrict__ bk,
    const unsigned short* __restrict__ Wvb, const float* __restrict__ bv,
    unsigned short* Qw, unsigned short* Kw, unsigned short* Vtw)
{
  __shared__ __align__(16) unsigned short smem[16384];  // 32KB: A[8192] B[8192]
  const int z = blockIdx.z;
  // Q scale folds 1/sqrt(d) AND log2(e) so attention uses exp2 directly.
  if (z == 0)      gemm_async_body<0>(smem, smem + 8192, Xb, Wqb, bq, Qw, 0.125f * 1.44269504f);
  else if (z == 1) gemm_async_body<0>(smem, smem + 8192, Xb, Wkb, bk, Kw, 1.0f);
  else             gemm_async_body<1>(smem, smem + 8192, Xb, Wvb, bv, Vtw, 1.0f);
}

// proj with pre-converted bf16 Wp — identical structure to a qkv slice.
__global__ __launch_bounds__(256) void proj_gemm_pre(
    const unsigned short* __restrict__ Yb,
    const unsigned short* __restrict__ Wpb, const float* __restrict__ bp,
    float* __restrict__ out)
{
  __shared__ __align__(16) unsigned short smem[16384];
  gemm_async_body<2>(smem, smem + 8192, Yb, Wpb, bp, (unsigned short*)out, 1.0f);
}

// Wave-per-strip-pair flash attention (BALANCED: every block = 34 tiles).
// R15 = R13 config (measured best, 251.9us total): 4-wave blocks, KVBLK=64,
// incremental staging pointers. R14's 2-wave variant regressed (79.6 vs 78.2)
// — barrier scope / intra-block balance were not binding; attn is per-wave
// dependency-chain bound (QK->exp2->cvt_pk->permlane->PV) at its structural
// 8 waves/CU, ~900 TF effective = the documented ~36%-of-peak plateau for
// 2-barrier kernels. Further gain needs the 8-phase counted-vmcnt template.
// XCD-aware grid (R10-verified: FETCH 147.5 -> 34MB): (bh=64, p=8), XCD=bh%8.
// TRANSPOSED algebra:
//   S^T = K.Q^T (C-layout: col=q on m16, row=key=quad*4+r per 16-block jn)
//   O^T = V^T.P^T; P^T B-frag built ENTIRELY in-register via
//   permlane32_swap + permlane16_swap pairs (verified: 0 bank conflicts).
// VALU diet (R5, verified): cvt_pk pack; lsum via ones-row MFMA (lane's
// lz[s][0] = full denominator, no shuffles in writeout).
// s_setprio(1) wrapped around MFMA clusters (T5, attn-positive per m191).
__global__ __launch_bounds__(256) void attn_pair(
    const unsigned short* __restrict__ Q,
    const unsigned short* __restrict__ Kg,
    const unsigned short* __restrict__ Vt,
    unsigned short* __restrict__ Y)
{
  __shared__ __align__(16) unsigned short KV[2 * 8192];  // [buf][K 4096h | V 4096h]

  const int tid  = threadIdx.x;
  const int wave = tid >> 6;
  const int lane = tid & 63;
  const int m16  = lane & 15;
  const int quad = lane >> 4;

  const int bh = blockIdx.x;                  // bh fastest -> XCD = bh%8
  const int p  = blockIdx.y;                  // 0..7
  const int b = bh >> 4, h = bh & 15;

  const unsigned short* Kb = Kg + (size_t)(b * Tt) * Cc + h * Dd;
  const unsigned short* Vb = Vt + (size_t)(b * Cc + h * Dd) * Tt;

  const int maxH = 32 - 2 * p;
  const int TOT  = 34;                        // maxH + (2p+2), constant
  const int chp  = quad ^ ((m16 >> 1) & 3);   // swizzled read channel

  bf16x8 onesA;
#pragma unroll
  for (int i = 0; i < 8; ++i) onesA[i] = (short)0x3F80;  // bf16 1.0

  // staging: constant per-thread offsets; pointers advance by fixed strides
  const unsigned short* pK[2];
  const unsigned short* pV[2];
#pragma unroll
  for (int ii = 0; ii < 2; ++ii) {
    const int cc  = ii * 256 + tid;
    const int kkS = cc >> 8;
    const int rrS = (cc >> 2) & 63;
    const int chd = (cc & 3) ^ ((rrS >> 1) & 3);
    pK[ii] = Kb + (size_t)rrS * Cc + kkS * 32 + chd * 8;
    pV[ii] = Vb + (size_t)rrS * Tt + kkS * 32 + chd * 8;
  }
  const unsigned short* pK0[2] = {pK[0], pK[1]};  // tile-0 bases (for wrap reset)
  const unsigned short* pV0[2] = {pV[0], pV[1]};

  // phase-0 (heavy) strip state
  int sidx = 63 - 4 * p - wave;
  int qw = sidx * 32;
  int nk = (sidx >> 1) + 1;
  bf16x8 qf[2][2];
  {
    const unsigned short* Qb = Q + (size_t)(b * Tt + qw) * Cc + h * Dd;
#pragma unroll
    for (int s = 0; s < 2; ++s)
#pragma unroll
      for (int kk = 0; kk < 2; ++kk)
        qf[s][kk] = *(const bf16x8*)(Qb + (size_t)(s * 16 + m16) * Cc + kk * 32 + quad * 8);
  }
  f32x4 o[2][4] = {};
  f32x4 lz[2] = {};                           // ones-MFMA denominator accumulator

  auto writeout = [&](int qw_) {
#pragma unroll
    for (int s = 0; s < 2; ++s) {
      const float l = lz[s][0];               // full sum for q=m16, no shuffle
      const float inv = (l > 0.f) ? (1.0f / l) : 0.f;
      const int t = qw_ + s * 16 + m16;
      unsigned short* yp = Y + (size_t)(b * Tt + t) * Cc + h * Dd + quad * 4;
#pragma unroll
      for (int jn = 0; jn < 4; ++jn) {
        uint2 pk;
        pk.x = cvtpk2bf(o[s][jn][0] * inv, o[s][jn][1] * inv);
        pk.y = cvtpk2bf(o[s][jn][2] * inv, o[s][jn][3] * inv);
        *(uint2*)(yp + jn * 16) = pk;
      }
    }
  };

  // prologue: stage tile 0 into buf 0, then advance pointers to tile 1
  {
    char* KbufB = (char*)KV;
    char* VbufB = KbufB + 8192;
#pragma unroll
    for (int ii = 0; ii < 2; ++ii) {
      async_copy16(KbufB + ii * 4096 + wave * 1024, pK[ii]);
      async_copy16(VbufB + ii * 4096 + wave * 1024, pV[ii]);
    }
#pragma unroll
    for (int ii = 0; ii < 2; ++ii) { pK[ii] += 64 * Cc; pV[ii] += 64; }
  }

  for (int g = 0; g < TOT; ++g) {
    if (g == maxH) {                          // heavy strip done -> switch to light
      writeout(qw);
      sidx = 4 * p + wave;
      qw = sidx * 32;
      nk = (sidx >> 1) + 1;
      const unsigned short* Qb = Q + (size_t)(b * Tt + qw) * Cc + h * Dd;
#pragma unroll
      for (int s = 0; s < 2; ++s) {
#pragma unroll
        for (int kk = 0; kk < 2; ++kk)
          qf[s][kk] = *(const bf16x8*)(Qb + (size_t)(s * 16 + m16) * Cc + kk * 32 + quad * 8);
#pragma unroll
        for (int jn = 0; jn < 4; ++jn)
          o[s][jn] = f32x4{0.f, 0.f, 0.f, 0.f};
        lz[s] = f32x4{0.f, 0.f, 0.f, 0.f};
      }
    }
    const int kt  = (g < maxH) ? g : g - maxH;
    const int k0  = kt * 64;
    const int buf = g & 1;

    __syncthreads();                          // copies for g drained; prior LDS reads done
    if (g + 1 < TOT) {                        // prefetch tile g+1 into other buffer
      if (g + 1 == maxH) {                    // wrap: light phase restarts at tile 0
#pragma unroll
        for (int ii = 0; ii < 2; ++ii) { pK[ii] = pK0[ii]; pV[ii] = pV0[ii]; }
      }
      char* KbufB = (char*)KV + (buf ^ 1) * 16384;
      char* VbufB = KbufB + 8192;
#pragma unroll
      for (int ii = 0; ii < 2; ++ii) {
        async_copy16(KbufB + ii * 4096 + wave * 1024, pK[ii]);
        async_copy16(VbufB + ii * 4096 + wave * 1024, pV[ii]);
      }
#pragma unroll
      for (int ii = 0; ii < 2; ++ii) { pK[ii] += 64 * Cc; pV[ii] += 64; }
    }

    if (kt < nk) {                            // wave-uniform; barriers stay outside
      const unsigned short* Kbuf = KV + buf * 8192;
      const unsigned short* Vbuf = Kbuf + 4096;
      bf16x8 kf[2][4], vf[2][4];
#pragma unroll
      for (int kk = 0; kk < 2; ++kk)
#pragma unroll
        for (int jn = 0; jn < 4; ++jn) {
          kf[kk][jn] = *(const bf16x8*)(Kbuf + kk * 2048 + (jn * 16 + m16) * 32 + chp * 8);
          vf[kk][jn] = *(const bf16x8*)(Vbuf + kk * 2048 + (jn * 16 + m16) * 32 + chp * 8);
        }

#pragma unroll
      for (int s = 0; s < 2; ++s) {
        const int smin = qw + s * 16;
        if (k0 > smin + 15) continue;         // sub-strip fully masked
        // S^T = K.Q^T : C-layout lane m16 = q, reg (jn,r) = key jn*16+quad*4+r
        f32x4 sv[4] = {};
        __builtin_amdgcn_s_setprio(1);
#pragma unroll
        for (int kk = 0; kk < 2; ++kk)
#pragma unroll
          for (int jn = 0; jn < 4; ++jn)
            sv[jn] = __builtin_amdgcn_mfma_f32_16x16x32_bf16(kf[kk][jn], qf[s][kk], sv[jn], 0, 0, 0);
        __builtin_amdgcn_s_setprio(0);

        if (k0 + 63 <= smin) {                // fully unmasked: bare exp2
#pragma unroll
          for (int jn = 0; jn < 4; ++jn)
#pragma unroll
            for (int r = 0; r < 4; ++r)
              sv[jn][r] = __builtin_exp2f(sv[jn][r]);
        } else {                               // diagonal: causal mask
          const int qcol = smin + m16;
#pragma unroll
          for (int jn = 0; jn < 4; ++jn)
#pragma unroll
            for (int r = 0; r < 4; ++r)
              sv[jn][r] = (k0 + jn * 16 + quad * 4 + r > qcol)
                              ? 0.f : __builtin_exp2f(sv[jn][r]);
        }

        // pack key-pairs into bf16x2 words (1 cvt_pk each)
        unsigned int P2[4][2];
#pragma unroll
        for (int jn = 0; jn < 4; ++jn) {
          P2[jn][0] = cvtpk2bf(sv[jn][0], sv[jn][1]);
          P2[jn][1] = cvtpk2bf(sv[jn][2], sv[jn][3]);
        }
        // in-register P^T B-frag build: 2 permlane ops per word-pair
#pragma unroll
        for (int kk = 0; kk < 2; ++kk) {
          auto r0 = __builtin_amdgcn_permlane32_swap(P2[2 * kk][0], P2[2 * kk + 1][0], false, false);
          auto t0 = __builtin_amdgcn_permlane16_swap(r0[0], r0[1], false, false);
          auto r1 = __builtin_amdgcn_permlane32_swap(P2[2 * kk][1], P2[2 * kk + 1][1], false, false);
          auto t1 = __builtin_amdgcn_permlane16_swap(r1[0], r1[1], false, false);
          uint4 u;
          u.x = t0[0];                        // sigma=0, w=0
          u.y = t1[0];                        // sigma=0, w=1
          u.z = t0[1];                        // sigma=1, w=0
          u.w = t1[1];                        // sigma=1, w=1
          union { uint4 u4; bf16x8 bf; } cv; cv.u4 = u;
          // O^T += V^T . P^T ; lz += ones . P^T (denominator on matrix pipe)
          __builtin_amdgcn_s_setprio(1);
          lz[s] = __builtin_amdgcn_mfma_f32_16x16x32_bf16(onesA, cv.bf, lz[s], 0, 0, 0);
#pragma unroll
          for (int jn = 0; jn < 4; ++jn)
            o[s][jn] = __builtin_amdgcn_mfma_f32_16x16x32_bf16(vf[kk][jn], cv.bf, o[s][jn], 0, 0, 0);
          __builtin_amdgcn_s_setprio(0);
        }
      }
    }
  }

  writeout(qw);                               // light strip
}

// proj fallback (ws too small for Wpb): A = Yw bf16 (async staging),
// B = Wp f32 (register-convert, dbuf: T14 issue-early/write-late), f32 out.
__global__ __launch_bounds__(256) void proj_gemm(
    const unsigned short* __restrict__ Y,
    const float* __restrict__ Wp, const float* __restrict__ bp,
    float* __restrict__ out)
{
  __shared__ __align__(16) unsigned short As[8192];   // [2][4096]
  __shared__ __align__(16) unsigned short Bs[8192];   // [2][4096]
  const int tid  = threadIdx.x;
  const int wave = tid >> 6;
  const int lane = tid & 63;
  const int m16  = lane & 15;
  const int quad = lane >> 4;
  const int row0 = blockIdx.x * 128;
  const int col0 = blockIdx.y * 128;
  const int wm = (wave >> 1) * 64;
  const int wn = (wave & 1) * 64;
  const int chp = quad ^ ((m16 >> 1) & 3);    // swizzled read channel

  f32x4 acc[4][4] = {};

  const int c0 = tid, c1 = 256 + tid;
  const int sw0 = (c0 & 3) ^ ((c0 >> 3) & 3);
  const int sw1 = (c1 & 3) ^ ((c1 >> 3) & 3);
  const unsigned short* Ag0 = Y + (size_t)(row0 + (c0 >> 2)) * Cc + sw0 * 8;
  const unsigned short* Ag1 = Y + (size_t)(row0 + (c1 >> 2)) * Cc + sw1 * 8;
  const float* Bg0 = Wp + (size_t)(col0 + (c0 >> 2)) * Cc + (c0 & 3) * 8;
  const float* Bg1 = Wp + (size_t)(col0 + (c1 >> 2)) * Cc + (c1 & 3) * 8;
  // swizzled LDS write offsets for the B panel (shorts)
  const int bd0 = ((c0 >> 2) * 4 + sw0) * 8;
  const int bd1 = ((c1 >> 2) * 4 + sw1) * 8;

  uint4 b0 = ldconv_f32(Bg0);
  uint4 b1 = ldconv_f32(Bg1);

  // prologue: stage A k=0 into buf0; write B k=0 into buf0; preload B k=32
  async_copy16((char*)As + wave * 1024,        Ag0);
  async_copy16((char*)As + 4096 + wave * 1024, Ag1);
  *(uint4*)(Bs + bd0) = b0;
  *(uint4*)(Bs + bd1) = b1;
  b0 = ldconv_f32(Bg0 + 32);
  b1 = ldconv_f32(Bg1 + 32);

  int buf = 0;
  for (int k0 = 0; k0 < Cc; k0 += 32) {
    __syncthreads();                          // buf A-copies drained; buf B-writes visible
    if (k0 + 32 < Cc) {
      char* Ab = (char*)As + (buf ^ 1) * 8192;
      async_copy16(Ab + wave * 1024,        Ag0 + k0 + 32);
      async_copy16(Ab + 4096 + wave * 1024, Ag1 + k0 + 32);
      *(uint4*)(Bs + (buf ^ 1) * 4096 + bd0) = b0;
      *(uint4*)(Bs + (buf ^ 1) * 4096 + bd1) = b1;
      if (k0 + 64 < Cc) {
        b0 = ldconv_f32(Bg0 + k0 + 64);
        b1 = ldconv_f32(Bg1 + k0 + 64);
      }
    }
    const unsigned short* Asb = As + buf * 4096;
    const unsigned short* Bsb = Bs + buf * 4096;
    bf16x8 af[4], bfr[4];
#pragma unroll
    for (int i = 0; i < 4; ++i)
      af[i] = *(const bf16x8*)(Asb + (wm + i * 16 + m16) * 32 + chp * 8);
#pragma unroll
    for (int j = 0; j < 4; ++j)
      bfr[j] = *(const bf16x8*)(Bsb + (wn + j * 16 + m16) * 32 + chp * 8);
#pragma unroll
    for (int i = 0; i < 4; ++i)
#pragma unroll
      for (int j = 0; j < 4; ++j)
        acc[i][j] = __builtin_amdgcn_mfma_f32_16x16x32_bf16(af[i], bfr[j], acc[i][j], 0, 0, 0);
    buf ^= 1;
  }

#pragma unroll
  for (int i = 0; i < 4; ++i) {
    const int rbase = row0 + wm + i * 16 + quad * 4;
#pragma unroll
    for (int j = 0; j < 4; ++j) {
      const int col = col0 + wn + j * 16 + m16;
      const float bv = bp[col];
#pragma unroll
      for (int r = 0; r < 4; ++r)
        out[(size_t)(rbase + r) * Cc + col] = acc[i][j][r] + bv;
    }
  }
}

extern "C" void kernel_launch(void* const* d_in, const int* in_sizes, int n_in,
                              void* d_out, int out_size, void* d_ws, size_t ws_size,
                              hipStream_t stream)
{
  const float* x  = (const float*)d_in[0];
  const float* Wq = (const float*)d_in[1];
  const float* bq = (const float*)d_in[2];
  const float* Wk = (const float*)d_in[3];
  const float* bk = (const float*)d_in[4];
  const float* Wv = (const float*)d_in[5];
  const float* bv = (const float*)d_in[6];
  const float* Wp = (const float*)d_in[7];
  const float* bp = (const float*)d_in[8];

  unsigned short* ws  = (unsigned short*)d_ws;
  unsigned short* Qw  = ws;                          // bf16 [8192][1024] (scale folded)
  unsigned short* Kw  = ws + (size_t)1 * XN;         // bf16 [8192][1024]
  unsigned short* Vtw = ws + (size_t)2 * XN;         // bf16 [b*1024 + n][2048]
  unsigned short* Yw  = ws + (size_t)3 * XN;         // bf16 [8192][1024]
  unsigned short* Wpb = ws + (size_t)4 * XN;         // bf16 [1024][1024] (if ws fits)
  const bool pre = ws_size >= ((size_t)4 * XN + WN) * sizeof(unsigned short);

  // d_out doubles as bf16 scratch for converted X/Wq/Wk/Wv; proj overwrites last.
  unsigned short* cvt = (unsigned short*)d_out;
  unsigned short* Xb  = cvt;
  unsigned short* Wqb = cvt + XN;
  unsigned short* Wkb = cvt + XN + WN;
  unsigned short* Wvb = cvt + XN + 2 * WN;
  float* out = (float*)d_out;

  convert_all<<<pre ? 6144 : 5632, 256, 0, stream>>>(x, Wq, Wk, Wv, cvt, Wp, Wpb);
  qkv_gemm<<<dim3(64, 8, 3), 256, 0, stream>>>(Xb, Wqb, bq, Wkb, bk, Wvb, bv, Qw, Kw, Vtw);
  attn_pair<<<dim3(64, 8), 256, 0, stream>>>(Qw, Kw, Vtw, Yw);  // bh fastest -> XCD=bh%8
  if (pre) proj_gemm_pre<<<dim3(64, 8), 256, 0, stream>>>(Yw, Wpb, bp, out);
  else     proj_gemm<<<dim3(64, 8), 256, 0, stream>>>(Yw, Wp, bp, out);
}